// Round 5
// baseline (19.450 us; speedup 1.0000x reference)
//
#include <hip/hip_runtime.h>

// Dempster-Shafer Wasserstein-like distance, n=3 classes (C=4), FOCAL=1.
// Per pixel closed form (h = x3/2, q = h*h/3):
//   out[0]=0                 out[4]=(x2+h)^2+q
//   out[1]=(x0+h-1)^2+q      out[5]=(x0+x2+h-1)^2+q
//   out[2]=(x1+h)^2+q        out[6]=(x1+x2+h)^2+q
//   out[3]=(x0+x1+h-1)^2+q   out[7]=0
//
// 4 output float4 per thread, staggered by 256 inside the block so every
// store instruction stays perfectly lane-contiguous (lane l -> base+16*l).
// 4 loads + 4 stores in flight per thread (deep MLP), 3744 blocks exact.
// Parity (lo/hi half of the 8-float pixel row) is uniform per thread: t&1.
// NO nontemporal ops (R2: nt bypasses L2 write-merging, 2x WRITE_SIZE).

typedef float fvec4 __attribute__((ext_vector_type(4)));

__device__ __forceinline__ fvec4 compute_half(const fvec4 x, bool hi) {
    float h = 0.5f * x.w;
    float q = h * h * (1.0f / 3.0f);

    float c0 = x.z + h;                                   // b4 (hi)
    float c1 = hi ? (x.x + x.z + h - 1.0f)                // b5
                  : (x.x + h - 1.0f);                     // b1
    float c2 = hi ? (x.y + x.z + h)                       // b6
                  : (x.y + h);                            // b2
    float c3 = x.x + x.y + h - 1.0f;                      // b3 (lo)

    fvec4 o;
    o.x = hi ? (c0 * c0 + q) : 0.0f;
    o.y = c1 * c1 + q;
    o.z = c2 * c2 + q;
    o.w = hi ? 0.0f : (c3 * c3 + q);
    return o;
}

__global__ __launch_bounds__(256) void wasserstein_ds_kernel(
    const fvec4* __restrict__ in,    // [npix] of (x0,x1,x2,x3)
    fvec4* __restrict__ out)         // [npix*2]
{
    int t = threadIdx.x;
    int outBase = blockIdx.x * 1024;           // 4 * 256 float4s per block
    int pixBase = outBase >> 1;
    bool hi = (t & 1) != 0;

    int p0 = pixBase + (t >> 1);

    // Issue all 4 loads back-to-back (compiler keeps them in flight).
    fvec4 x0 = in[p0];
    fvec4 x1 = in[p0 + 128];
    fvec4 x2 = in[p0 + 256];
    fvec4 x3 = in[p0 + 384];

    fvec4 o0 = compute_half(x0, hi);
    fvec4 o1 = compute_half(x1, hi);
    fvec4 o2 = compute_half(x2, hi);
    fvec4 o3 = compute_half(x3, hi);

    out[outBase + t]       = o0;
    out[outBase + 256 + t] = o1;
    out[outBase + 512 + t] = o2;
    out[outBase + 768 + t] = o3;
}

extern "C" void kernel_launch(void* const* d_in, const int* in_sizes, int n_in,
                              void* d_out, int out_size, void* d_ws, size_t ws_size,
                              hipStream_t stream) {
    const fvec4* in = (const fvec4*)d_in[0];
    fvec4* out = (fvec4*)d_out;
    int npix = in_sizes[0] / 4;          // B*H*W = 1,916,928
    int nout4 = npix * 2;                // 3,833,856
    int grid = nout4 / 1024;             // 3744 exact (no tail)

    wasserstein_ds_kernel<<<grid, 256, 0, stream>>>(in, out);
}

// Round 6
// 17.167 us; speedup vs baseline: 1.1330x; 1.1330x over previous
//
#include <hip/hip_runtime.h>

// Dempster-Shafer Wasserstein-like distance, n=3 classes (C=4), FOCAL=1.
// Per pixel closed form (h = x3/2, q = h*h/3):
//   out[0]=0                 out[4]=(x2+h)^2+q
//   out[1]=(x0+h-1)^2+q      out[5]=(x0+x2+h-1)^2+q
//   out[2]=(x1+h)^2+q        out[6]=(x1+x2+h)^2+q
//   out[3]=(x0+x1+h-1)^2+q   out[7]=0
//
// 4 output float4 per thread, staggered by 256 inside the block: every
// store instruction is 1KB fully contiguous per wave (lane l -> base+16*l,
// each 64B line covered by 4 lanes of the SAME instruction) -> nt stores
// emit full-line transactions, no partial-line amplification (R3's bug was
// nt + 64B lane stride = 4 partial writes per line from different instrs).
// nt stores bypass L2/L3 -> L3 stays dedicated to the 30.7MB input, which
// becomes fully L3-resident across replays -> HBM traffic ~= 61MB writes.
// Loads stay CACHED (we want input in L3).

typedef float fvec4 __attribute__((ext_vector_type(4)));

__device__ __forceinline__ fvec4 compute_half(const fvec4 x, bool hi) {
    float h = 0.5f * x.w;
    float q = h * h * (1.0f / 3.0f);

    float c0 = x.z + h;                                   // b4 (hi)
    float c1 = hi ? (x.x + x.z + h - 1.0f)                // b5
                  : (x.x + h - 1.0f);                     // b1
    float c2 = hi ? (x.y + x.z + h)                       // b6
                  : (x.y + h);                            // b2
    float c3 = x.x + x.y + h - 1.0f;                      // b3 (lo)

    fvec4 o;
    o.x = hi ? (c0 * c0 + q) : 0.0f;
    o.y = c1 * c1 + q;
    o.z = c2 * c2 + q;
    o.w = hi ? 0.0f : (c3 * c3 + q);
    return o;
}

__global__ __launch_bounds__(256) void wasserstein_ds_kernel(
    const fvec4* __restrict__ in,    // [npix] of (x0,x1,x2,x3)
    fvec4* __restrict__ out)         // [npix*2]
{
    int t = threadIdx.x;
    int outBase = blockIdx.x * 1024;           // 4 * 256 float4s per block
    int pixBase = outBase >> 1;
    bool hi = (t & 1) != 0;

    int p0 = pixBase + (t >> 1);

    fvec4 x0 = in[p0];
    fvec4 x1 = in[p0 + 128];
    fvec4 x2 = in[p0 + 256];
    fvec4 x3 = in[p0 + 384];

    fvec4 o0 = compute_half(x0, hi);
    fvec4 o1 = compute_half(x1, hi);
    fvec4 o2 = compute_half(x2, hi);
    fvec4 o3 = compute_half(x3, hi);

    __builtin_nontemporal_store(o0, &out[outBase + t]);
    __builtin_nontemporal_store(o1, &out[outBase + 256 + t]);
    __builtin_nontemporal_store(o2, &out[outBase + 512 + t]);
    __builtin_nontemporal_store(o3, &out[outBase + 768 + t]);
}

extern "C" void kernel_launch(void* const* d_in, const int* in_sizes, int n_in,
                              void* d_out, int out_size, void* d_ws, size_t ws_size,
                              hipStream_t stream) {
    const fvec4* in = (const fvec4*)d_in[0];
    fvec4* out = (fvec4*)d_out;
    int npix = in_sizes[0] / 4;          // B*H*W = 1,916,928
    int nout4 = npix * 2;                // 3,833,856
    int grid = nout4 / 1024;             // 3744 exact (no tail)

    wasserstein_ds_kernel<<<grid, 256, 0, stream>>>(in, out);
}

// Round 7
// 16.669 us; speedup vs baseline: 1.1668x; 1.0298x over previous
//
#include <hip/hip_runtime.h>

// Dempster-Shafer Wasserstein-like distance, n=3 classes (C=4), FOCAL=1.
// Per pixel closed form (h = x3/2, q = h*h/3):
//   out[0]=0                 out[4]=(x2+h)^2+q
//   out[1]=(x0+h-1)^2+q      out[5]=(x0+x2+h-1)^2+q
//   out[2]=(x1+h)^2+q        out[6]=(x1+x2+h)^2+q
//   out[3]=(x0+x1+h-1)^2+q   out[7]=0
//
// Block tile: 512 pixels -> 1024 output float4.
// Phase 1: 2 UNIQUE fully-coalesced float4 loads per thread (1KB/wave each),
//          staged to LDS in SoA (4 planes x 512 floats, 4B/lane stride =
//          bank-conflict-free writes).
// Phase 2: one thread per output float4; x read from LDS planes (2 lanes
//          share an address -> broadcast, 2/bank = free); 4 nt stores, each
//          1KB fully lane-contiguous (full 64B lines within one instruction,
//          so nt streams without write amplification — R3's failure mode).
// nt stores bypass L2/L3 so the 30.7MB input stays cache-resident across
// replays; writes stream at HBM wire speed.

typedef float fvec4 __attribute__((ext_vector_type(4)));

__device__ __forceinline__ fvec4 compute_half(const fvec4 x, bool hi) {
    float h = 0.5f * x.w;
    float q = h * h * (1.0f / 3.0f);

    float c0 = x.z + h;                                   // b4 (hi)
    float c1 = hi ? (x.x + x.z + h - 1.0f)                // b5
                  : (x.x + h - 1.0f);                     // b1
    float c2 = hi ? (x.y + x.z + h)                       // b6
                  : (x.y + h);                            // b2
    float c3 = x.x + x.y + h - 1.0f;                      // b3 (lo)

    fvec4 o;
    o.x = hi ? (c0 * c0 + q) : 0.0f;
    o.y = c1 * c1 + q;
    o.z = c2 * c2 + q;
    o.w = hi ? 0.0f : (c3 * c3 + q);
    return o;
}

__global__ __launch_bounds__(256) void wasserstein_ds_kernel(
    const fvec4* __restrict__ in,    // [npix]
    fvec4* __restrict__ out)         // [npix*2]
{
    __shared__ float plane[4][512];  // SoA input stage, 8KB

    int t = threadIdx.x;
    int pixBase = blockIdx.x * 512;
    int outBase = blockIdx.x * 1024;

    // Phase 1: unique coalesced loads -> LDS SoA (conflict-free b32 writes).
    fvec4 xa = in[pixBase + t];
    fvec4 xb = in[pixBase + 256 + t];
    plane[0][t] = xa.x;  plane[1][t] = xa.y;
    plane[2][t] = xa.z;  plane[3][t] = xa.w;
    plane[0][256 + t] = xb.x;  plane[1][256 + t] = xb.y;
    plane[2][256 + t] = xb.z;  plane[3][256 + t] = xb.w;

    __syncthreads();

    // Phase 2: one output float4 per (thread, group); contiguous nt stores.
    bool hi = (t & 1) != 0;
    int half = t >> 1;

    #pragma unroll
    for (int g = 0; g < 4; ++g) {
        int P = 128 * g + half;
        fvec4 x;
        x.x = plane[0][P];
        x.y = plane[1][P];
        x.z = plane[2][P];
        x.w = plane[3][P];
        fvec4 o = compute_half(x, hi);
        __builtin_nontemporal_store(o, &out[outBase + 256 * g + t]);
    }
}

extern "C" void kernel_launch(void* const* d_in, const int* in_sizes, int n_in,
                              void* d_out, int out_size, void* d_ws, size_t ws_size,
                              hipStream_t stream) {
    const fvec4* in = (const fvec4*)d_in[0];
    fvec4* out = (fvec4*)d_out;
    int npix = in_sizes[0] / 4;          // B*H*W = 1,916,928
    int nout4 = npix * 2;                // 3,833,856
    int grid = nout4 / 1024;             // 3744 exact (no tail)

    wasserstein_ds_kernel<<<grid, 256, 0, stream>>>(in, out);
}